// Round 1
// baseline (14532.069 us; speedup 1.0000x reference)
//
#include <hip/hip_runtime.h>
#include <hip/hip_bf16.h>

#define LAYERS 8
#define BATCH 2
#define SEQ 2048
#define CH 1024
#define NH 16
#define MROWS (BATCH*SEQ)   // 4096

typedef __attribute__((ext_vector_type(8))) short bf16x8;
typedef __attribute__((ext_vector_type(4))) float f32x4;

__device__ __forceinline__ float bf2f(unsigned int u) {
  union { unsigned int i; float f; } v; v.i = u << 16; return v.f;
}
__device__ __forceinline__ unsigned short f2bf(float f) {
  union { float f; unsigned int i; } v; v.f = f;
  unsigned int x = v.i;
  unsigned int r = (x + 0x7fffu + ((x >> 16) & 1u)) >> 16;
  return (unsigned short)r;
}

// ---------------- LayerNorm: f32 in -> bf16 (and/or f32) out ----------------
template<bool OUT_BF>
__global__ __launch_bounds__(256) void ln_kernel(
    const float* __restrict__ x, const float* __restrict__ g,
    const float* __restrict__ bta, unsigned short* __restrict__ outb,
    float* __restrict__ outf)
{
  int row = blockIdx.x;
  int tid = threadIdx.x;
  const float4* xr = reinterpret_cast<const float4*>(x + (size_t)row * CH);
  float4 v = xr[tid];
  float s  = v.x + v.y + v.z + v.w;
  float s2 = v.x*v.x + v.y*v.y + v.z*v.z + v.w*v.w;
  #pragma unroll
  for (int off = 32; off > 0; off >>= 1) {
    s  += __shfl_xor(s,  off, 64);
    s2 += __shfl_xor(s2, off, 64);
  }
  __shared__ float red[8];
  int wid = tid >> 6;
  if ((tid & 63) == 0) { red[wid] = s; red[wid + 4] = s2; }
  __syncthreads();
  s  = red[0] + red[1] + red[2] + red[3];
  s2 = red[4] + red[5] + red[6] + red[7];
  float mean = s * (1.0f / CH);
  float var  = s2 * (1.0f / CH) - mean * mean;
  float rstd = rsqrtf(var + 1e-5f);
  float4 gv = reinterpret_cast<const float4*>(g)[tid];
  float4 bv = reinterpret_cast<const float4*>(bta)[tid];
  float o0 = (v.x - mean) * rstd * gv.x + bv.x;
  float o1 = (v.y - mean) * rstd * gv.y + bv.y;
  float o2 = (v.z - mean) * rstd * gv.z + bv.z;
  float o3 = (v.w - mean) * rstd * gv.w + bv.w;
  if (OUT_BF) {
    ushort4 ob;
    ob.x = f2bf(o0); ob.y = f2bf(o1); ob.z = f2bf(o2); ob.w = f2bf(o3);
    reinterpret_cast<ushort4*>(outb + (size_t)row * CH)[tid] = ob;
  } else {
    float4 of; of.x = o0; of.y = o1; of.z = o2; of.w = o3;
    reinterpret_cast<float4*>(outf + (size_t)row * CH)[tid] = of;
  }
}

// ---------------- GEMM: C = A(bf16,[M,K]) * B(f32,[K,N]) + bias, epilogue ----
template<int DO_GELU, int DO_RES, int WF32, int WBF>
__global__ __launch_bounds__(256) void gemm_kernel(
    const unsigned short* __restrict__ A, const float* __restrict__ B,
    const float* __restrict__ bias, const float* __restrict__ res,
    float* __restrict__ outf, unsigned short* __restrict__ outb,
    int M, int N, int K)
{
  __shared__ unsigned short As[128][32];  // [m][k]
  __shared__ unsigned short Bs[128][32];  // [n][k]  (transposed staging)
  int tid = threadIdx.x;
  int m0 = blockIdx.y * 128, n0 = blockIdx.x * 128;
  int lane = tid & 63, wid = tid >> 6;
  int wr = wid >> 1, wc = wid & 1;
  int fr = lane & 15, fq = lane >> 4;

  f32x4 acc[4][4];
  #pragma unroll
  for (int i = 0; i < 4; i++)
    #pragma unroll
    for (int j = 0; j < 4; j++) acc[i][j] = (f32x4){0.f, 0.f, 0.f, 0.f};

  for (int kk = 0; kk < K; kk += 32) {
    // stage A: 512 chunks of 8 bf16, 2 per thread
    #pragma unroll
    for (int j = 0; j < 2; j++) {
      int c = tid * 2 + j;
      int row = c >> 2, kc = (c & 3) << 3;
      *reinterpret_cast<int4*>(&As[row][kc]) =
          *reinterpret_cast<const int4*>(A + (size_t)(m0 + row) * K + kk + kc);
    }
    // stage B transposed: thread reads 16 f32 of row (kk + tid>>3), writes column kk
    {
      int krow = tid >> 3;
      int nq = (tid & 7) << 4;
      const float* src = B + (size_t)(kk + krow) * N + n0 + nq;
      #pragma unroll
      for (int j4 = 0; j4 < 4; j4++) {
        float4 vv = reinterpret_cast<const float4*>(src)[j4];
        Bs[nq + j4*4 + 0][krow] = f2bf(vv.x);
        Bs[nq + j4*4 + 1][krow] = f2bf(vv.y);
        Bs[nq + j4*4 + 2][krow] = f2bf(vv.z);
        Bs[nq + j4*4 + 3][krow] = f2bf(vv.w);
      }
    }
    __syncthreads();
    bf16x8 af[4], bfr[4];
    #pragma unroll
    for (int i = 0; i < 4; i++) {
      af[i]  = *reinterpret_cast<const bf16x8*>(&As[wr*64 + i*16 + fr][fq*8]);
      bfr[i] = *reinterpret_cast<const bf16x8*>(&Bs[wc*64 + i*16 + fr][fq*8]);
    }
    #pragma unroll
    for (int i = 0; i < 4; i++)
      #pragma unroll
      for (int j = 0; j < 4; j++)
        acc[i][j] = __builtin_amdgcn_mfma_f32_16x16x32_bf16(af[i], bfr[j], acc[i][j], 0, 0, 0);
    __syncthreads();
  }

  // epilogue: C/D layout col=lane&15, row=(lane>>4)*4+reg
  #pragma unroll
  for (int j = 0; j < 4; j++) {
    int col = n0 + wc*64 + j*16 + fr;
    float bcol = bias[col];
    #pragma unroll
    for (int i = 0; i < 4; i++) {
      #pragma unroll
      for (int r = 0; r < 4; r++) {
        int row = m0 + wr*64 + i*16 + fq*4 + r;
        float val = acc[i][j][r] + bcol;
        if constexpr (DO_GELU) {
          float u = 0.7978845608028654f * (val + 0.044715f * val * val * val);
          float e = __expf(2.0f * u);
          float th = 1.0f - 2.0f / (e + 1.0f);
          val = 0.5f * val * (1.0f + th);
        }
        size_t idx = (size_t)row * N + col;
        if constexpr (DO_RES) val += res[idx];
        if constexpr (WF32) outf[idx] = val;
        if constexpr (WBF)  outb[idx] = f2bf(val);
      }
    }
  }
}

// ---------------- Flash attention: 1 thread per q row --------------------
__global__ __launch_bounds__(256) void attn_kernel(
    const unsigned short* __restrict__ qkv, unsigned short* __restrict__ y)
{
  int qt = blockIdx.x;       // q tile of 256 rows
  int bh = blockIdx.y;       // b*16 + h
  int b = bh >> 4, h = bh & 15;
  int tid = threadIdx.x;
  int q = qt * 256 + tid;
  __shared__ float Ks[64][64];
  __shared__ float Vs[64][64];
  const unsigned short* base = qkv + (size_t)b * SEQ * 3072 + h * 64;

  float qr[64];
  {
    const unsigned short* qsrc = base + (size_t)q * 3072;
    #pragma unroll
    for (int j = 0; j < 8; j++) {
      int4 raw = *reinterpret_cast<const int4*>(qsrc + j * 8);
      unsigned int a = raw.x, bb = raw.y, c = raw.z, d = raw.w;
      qr[j*8+0] = bf2f(a & 0xffffu); qr[j*8+1] = bf2f(a >> 16);
      qr[j*8+2] = bf2f(bb & 0xffffu); qr[j*8+3] = bf2f(bb >> 16);
      qr[j*8+4] = bf2f(c & 0xffffu); qr[j*8+5] = bf2f(c >> 16);
      qr[j*8+6] = bf2f(d & 0xffffu); qr[j*8+7] = bf2f(d >> 16);
    }
  }
  float o[64];
  #pragma unroll
  for (int d = 0; d < 64; d++) o[d] = 0.0f;
  float mrun = -1e30f, lrun = 0.0f;

  int ktend = qt * 256 + 256;
  for (int kt0 = 0; kt0 < ktend; kt0 += 64) {
    __syncthreads();
    {
      int r = tid >> 2, dq = (tid & 3) << 4;
      const unsigned short* ksrc = base + (size_t)(kt0 + r) * 3072 + 1024 + dq;
      const unsigned short* vsrc = base + (size_t)(kt0 + r) * 3072 + 2048 + dq;
      #pragma unroll
      for (int j = 0; j < 2; j++) {
        int4 raw = *reinterpret_cast<const int4*>(ksrc + j * 8);
        unsigned int a = raw.x, bb = raw.y, c = raw.z, d = raw.w;
        Ks[r][dq+j*8+0] = bf2f(a & 0xffffu); Ks[r][dq+j*8+1] = bf2f(a >> 16);
        Ks[r][dq+j*8+2] = bf2f(bb & 0xffffu); Ks[r][dq+j*8+3] = bf2f(bb >> 16);
        Ks[r][dq+j*8+4] = bf2f(c & 0xffffu); Ks[r][dq+j*8+5] = bf2f(c >> 16);
        Ks[r][dq+j*8+6] = bf2f(d & 0xffffu); Ks[r][dq+j*8+7] = bf2f(d >> 16);
        int4 rw2 = *reinterpret_cast<const int4*>(vsrc + j * 8);
        unsigned int a2 = rw2.x, b2 = rw2.y, c2 = rw2.z, d2 = rw2.w;
        Vs[r][dq+j*8+0] = bf2f(a2 & 0xffffu); Vs[r][dq+j*8+1] = bf2f(a2 >> 16);
        Vs[r][dq+j*8+2] = bf2f(b2 & 0xffffu); Vs[r][dq+j*8+3] = bf2f(b2 >> 16);
        Vs[r][dq+j*8+4] = bf2f(c2 & 0xffffu); Vs[r][dq+j*8+5] = bf2f(c2 >> 16);
        Vs[r][dq+j*8+6] = bf2f(d2 & 0xffffu); Vs[r][dq+j*8+7] = bf2f(d2 >> 16);
      }
    }
    __syncthreads();
    int kkend = q - kt0 + 1;
    if (kkend > 64) kkend = 64;
    for (int kk = 0; kk < kkend; kk++) {
      float s0 = 0.f, s1 = 0.f, s2 = 0.f, s3 = 0.f;
      #pragma unroll
      for (int d4 = 0; d4 < 16; d4++) {
        float4 kv = *reinterpret_cast<const float4*>(&Ks[kk][d4*4]);
        s0 = fmaf(qr[d4*4+0], kv.x, s0);
        s1 = fmaf(qr[d4*4+1], kv.y, s1);
        s2 = fmaf(qr[d4*4+2], kv.z, s2);
        s3 = fmaf(qr[d4*4+3], kv.w, s3);
      }
      float s = ((s0 + s1) + (s2 + s3)) * 0.125f;
      if (s > mrun) {
        float corr = __expf(mrun - s);
        mrun = s;
        lrun *= corr;
        #pragma unroll
        for (int d = 0; d < 64; d++) o[d] *= corr;
      }
      float p = __expf(s - mrun);
      lrun += p;
      #pragma unroll
      for (int d4 = 0; d4 < 16; d4++) {
        float4 vv = *reinterpret_cast<const float4*>(&Vs[kk][d4*4]);
        o[d4*4+0] = fmaf(p, vv.x, o[d4*4+0]);
        o[d4*4+1] = fmaf(p, vv.y, o[d4*4+1]);
        o[d4*4+2] = fmaf(p, vv.z, o[d4*4+2]);
        o[d4*4+3] = fmaf(p, vv.w, o[d4*4+3]);
      }
    }
  }
  float inv = 1.0f / lrun;
  unsigned short* dst = y + ((size_t)(b * SEQ + q)) * CH + h * 64;
  #pragma unroll
  for (int j = 0; j < 8; j++) {
    int4 pack;
    unsigned int w0 = (unsigned int)f2bf(o[j*8+0]*inv) | ((unsigned int)f2bf(o[j*8+1]*inv) << 16);
    unsigned int w1 = (unsigned int)f2bf(o[j*8+2]*inv) | ((unsigned int)f2bf(o[j*8+3]*inv) << 16);
    unsigned int w2 = (unsigned int)f2bf(o[j*8+4]*inv) | ((unsigned int)f2bf(o[j*8+5]*inv) << 16);
    unsigned int w3 = (unsigned int)f2bf(o[j*8+6]*inv) | ((unsigned int)f2bf(o[j*8+7]*inv) << 16);
    pack.x = (int)w0; pack.y = (int)w1; pack.z = (int)w2; pack.w = (int)w3;
    *reinterpret_cast<int4*>(dst + j*8) = pack;
  }
}

// ---------------- launch ----------------
extern "C" void kernel_launch(void* const* d_in, const int* in_sizes, int n_in,
                              void* d_out, int out_size, void* d_ws, size_t ws_size,
                              hipStream_t stream)
{
  const float* emb    = (const float*)d_in[0];
  const float* ln1_g  = (const float*)d_in[2];
  const float* ln1_b  = (const float*)d_in[3];
  const float* attn_w = (const float*)d_in[4];
  const float* attn_b = (const float*)d_in[5];
  const float* proj_w = (const float*)d_in[6];
  const float* proj_b = (const float*)d_in[7];
  const float* ln2_g  = (const float*)d_in[8];
  const float* ln2_b  = (const float*)d_in[9];
  const float* fc_w   = (const float*)d_in[10];
  const float* fc_b   = (const float*)d_in[11];
  const float* p2_w   = (const float*)d_in[12];
  const float* p2_b   = (const float*)d_in[13];
  const float* lnf_g  = (const float*)d_in[14];
  const float* lnf_b  = (const float*)d_in[15];

  char* ws = (char*)d_ws;
  float* x            = (float*)ws;                                    // 16777216 B
  unsigned short* qkv = (unsigned short*)(ws + 16777216);              // 25165824 B
  unsigned short* hb  = (unsigned short*)(ws + 16777216 + 25165824);   //  8388608 B
  unsigned short* mb  = (unsigned short*)(ws + 16777216 + 25165824 + 8388608); // 33554432 B

  hipMemcpyAsync(x, emb, (size_t)MROWS * CH * sizeof(float),
                 hipMemcpyDeviceToDevice, stream);

  for (int l = 0; l < LAYERS; l++) {
    ln_kernel<true><<<MROWS, 256, 0, stream>>>(
        x, ln1_g + (size_t)l*CH, ln1_b + (size_t)l*CH, hb, nullptr);
    gemm_kernel<0,0,0,1><<<dim3(3072/128, MROWS/128), 256, 0, stream>>>(
        hb, attn_w + (size_t)l*CH*3072, attn_b + (size_t)l*3072,
        nullptr, nullptr, qkv, MROWS, 3072, CH);
    attn_kernel<<<dim3(SEQ/256, BATCH*NH), 256, 0, stream>>>(qkv, hb);
    gemm_kernel<0,1,1,0><<<dim3(CH/128, MROWS/128), 256, 0, stream>>>(
        hb, proj_w + (size_t)l*CH*CH, proj_b + (size_t)l*CH,
        x, x, nullptr, MROWS, CH, CH);
    ln_kernel<true><<<MROWS, 256, 0, stream>>>(
        x, ln2_g + (size_t)l*CH, ln2_b + (size_t)l*CH, hb, nullptr);
    gemm_kernel<1,0,0,1><<<dim3(4096/128, MROWS/128), 256, 0, stream>>>(
        hb, fc_w + (size_t)l*CH*4096, fc_b + (size_t)l*4096,
        nullptr, nullptr, mb, MROWS, 4096, CH);
    gemm_kernel<0,1,1,0><<<dim3(CH/128, MROWS/128), 256, 0, stream>>>(
        mb, p2_w + (size_t)l*4096*CH, p2_b + (size_t)l*CH,
        x, x, nullptr, MROWS, CH, 4096);
  }
  ln_kernel<false><<<MROWS, 256, 0, stream>>>(
      x, lnf_g, lnf_b, nullptr, (float*)d_out);
}

// Round 2
// 3485.951 us; speedup vs baseline: 4.1688x; 4.1688x over previous
//
#include <hip/hip_runtime.h>
#include <hip/hip_bf16.h>

#define LAYERS 8
#define BATCH 2
#define SEQ 2048
#define CH 1024
#define NH 16
#define MROWS (BATCH*SEQ)   // 4096

typedef __attribute__((ext_vector_type(8))) short bf16x8;
typedef __attribute__((ext_vector_type(4))) float f32x4;

__device__ __forceinline__ float bf2f(unsigned int u) {
  union { unsigned int i; float f; } v; v.i = u << 16; return v.f;
}
__device__ __forceinline__ unsigned short f2bf(float f) {
  union { float f; unsigned int i; } v; v.f = f;
  unsigned int x = v.i;
  unsigned int r = (x + 0x7fffu + ((x >> 16) & 1u)) >> 16;
  return (unsigned short)r;
}

__device__ __forceinline__ void async16(const unsigned short* g, unsigned short* l) {
  __builtin_amdgcn_global_load_lds(
      (const __attribute__((address_space(1))) unsigned int*)g,
      (__attribute__((address_space(3))) unsigned int*)l, 16, 0, 0);
}

// ---------------- LayerNorm: f32 in -> bf16 (or f32) out ----------------
template<bool OUT_BF>
__global__ __launch_bounds__(256) void ln_kernel(
    const float* __restrict__ x, const float* __restrict__ g,
    const float* __restrict__ bta, unsigned short* __restrict__ outb,
    float* __restrict__ outf)
{
  int row = blockIdx.x;
  int tid = threadIdx.x;
  const float4* xr = reinterpret_cast<const float4*>(x + (size_t)row * CH);
  float4 v = xr[tid];
  float s  = v.x + v.y + v.z + v.w;
  float s2 = v.x*v.x + v.y*v.y + v.z*v.z + v.w*v.w;
  #pragma unroll
  for (int off = 32; off > 0; off >>= 1) {
    s  += __shfl_xor(s,  off, 64);
    s2 += __shfl_xor(s2, off, 64);
  }
  __shared__ float red[8];
  int wid = tid >> 6;
  if ((tid & 63) == 0) { red[wid] = s; red[wid + 4] = s2; }
  __syncthreads();
  s  = red[0] + red[1] + red[2] + red[3];
  s2 = red[4] + red[5] + red[6] + red[7];
  float mean = s * (1.0f / CH);
  float var  = s2 * (1.0f / CH) - mean * mean;
  float rstd = rsqrtf(var + 1e-5f);
  float4 gv = reinterpret_cast<const float4*>(g)[tid];
  float4 bv = reinterpret_cast<const float4*>(bta)[tid];
  float o0 = (v.x - mean) * rstd * gv.x + bv.x;
  float o1 = (v.y - mean) * rstd * gv.y + bv.y;
  float o2 = (v.z - mean) * rstd * gv.z + bv.z;
  float o3 = (v.w - mean) * rstd * gv.w + bv.w;
  if (OUT_BF) {
    ushort4 ob;
    ob.x = f2bf(o0); ob.y = f2bf(o1); ob.z = f2bf(o2); ob.w = f2bf(o3);
    reinterpret_cast<ushort4*>(outb + (size_t)row * CH)[tid] = ob;
  } else {
    float4 of; of.x = o0; of.y = o1; of.z = o2; of.w = o3;
    reinterpret_cast<float4*>(outf + (size_t)row * CH)[tid] = of;
  }
}

// ---------------- Weight transpose+convert: W[K,N] f32 -> Wt[N,K] bf16 ----
__global__ __launch_bounds__(256) void wt_kernel(
    const float* __restrict__ W, unsigned short* __restrict__ Wt, int K, int N)
{
  __shared__ float tile[32][33];
  int k0 = blockIdx.y * 32, n0 = blockIdx.x * 32;
  int tx = threadIdx.x & 31, ty = threadIdx.x >> 5;  // ty 0..7
  #pragma unroll
  for (int i = 0; i < 32; i += 8)
    tile[ty + i][tx] = W[(size_t)(k0 + ty + i) * N + n0 + tx];
  __syncthreads();
  #pragma unroll
  for (int i = 0; i < 32; i += 8)
    Wt[(size_t)(n0 + ty + i) * K + k0 + tx] = f2bf(tile[tx][ty + i]);
}

// ---------------- GEMM: C = A(bf16,[M,K]) * Bt(bf16,[N,K])^T + bias -------
template<int DO_GELU, int DO_RES, int WF32, int WBF>
__global__ __launch_bounds__(256) void gemm_bt_kernel(
    const unsigned short* __restrict__ A, const unsigned short* __restrict__ Bt,
    const float* __restrict__ bias, const float* __restrict__ res,
    float* __restrict__ outf, unsigned short* __restrict__ outb,
    int M, int N, int K)
{
  __shared__ unsigned short As[128][32];  // [m][k]
  __shared__ unsigned short Bs[128][32];  // [n][k]
  const int tid = threadIdx.x;
  const int m0 = blockIdx.y * 128, n0 = blockIdx.x * 128;
  const int lane = tid & 63, wid = tid >> 6;
  const int wr = wid >> 1, wc = wid & 1;
  const int fr = lane & 15, fq = lane >> 4;

  f32x4 acc[4][4];
  #pragma unroll
  for (int i = 0; i < 4; i++)
    #pragma unroll
    for (int j = 0; j < 4; j++) acc[i][j] = (f32x4){0.f, 0.f, 0.f, 0.f};

  const int r0 = tid >> 2,         k0c = (tid & 3) << 3;
  const int r1 = (256 + tid) >> 2, k1c = (tid & 3) << 3;   // second chunk: rows 64..127
  const unsigned short* a0 = A  + (size_t)(m0 + r0) * K + k0c;
  const unsigned short* a1 = A  + (size_t)(m0 + r1) * K + k1c;
  const unsigned short* b0 = Bt + (size_t)(n0 + r0) * K + k0c;
  const unsigned short* b1 = Bt + (size_t)(n0 + r1) * K + k1c;

  for (int kk = 0; kk < K; kk += 32) {
    async16(a0 + kk, &As[r0][k0c]);
    async16(a1 + kk, &As[r1][k1c]);
    async16(b0 + kk, &Bs[r0][k0c]);
    async16(b1 + kk, &Bs[r1][k1c]);
    __syncthreads();
    bf16x8 af[4], bfr[4];
    #pragma unroll
    for (int i = 0; i < 4; i++) {
      af[i]  = *reinterpret_cast<const bf16x8*>(&As[wr*64 + i*16 + fr][fq*8]);
      bfr[i] = *reinterpret_cast<const bf16x8*>(&Bs[wc*64 + i*16 + fr][fq*8]);
    }
    #pragma unroll
    for (int i = 0; i < 4; i++)
      #pragma unroll
      for (int j = 0; j < 4; j++)
        acc[i][j] = __builtin_amdgcn_mfma_f32_16x16x32_bf16(af[i], bfr[j], acc[i][j], 0, 0, 0);
    __syncthreads();
  }

  #pragma unroll
  for (int j = 0; j < 4; j++) {
    int col = n0 + wc*64 + j*16 + fr;
    float bcol = bias[col];
    #pragma unroll
    for (int i = 0; i < 4; i++) {
      #pragma unroll
      for (int r = 0; r < 4; r++) {
        int row = m0 + wr*64 + i*16 + fq*4 + r;
        float val = acc[i][j][r] + bcol;
        if constexpr (DO_GELU) {
          float u = 0.7978845608028654f * (val + 0.044715f * val * val * val);
          float e = __expf(2.0f * u);
          float th = 1.0f - 2.0f / (e + 1.0f);
          val = 0.5f * val * (1.0f + th);
        }
        size_t idx = (size_t)row * N + col;
        if constexpr (DO_RES) val += res[idx];
        if constexpr (WF32) outf[idx] = val;
        if constexpr (WBF)  outb[idx] = f2bf(val);
      }
    }
  }
}

// ---------------- MFMA flash attention ------------------------------------
// block: 128 q rows (4 waves x 32), iterate kv tiles of 64.
__global__ __launch_bounds__(256) void attn_mfma_kernel(
    const unsigned short* __restrict__ qkv, unsigned short* __restrict__ y)
{
  __shared__ unsigned short Ks[64][72];      // [tok][d]
  __shared__ unsigned short Vt[64][72];      // [d][tok]
  __shared__ unsigned short Ps[4][16][72];   // per-wave [q][k]
  const int tid = threadIdx.x;
  const int lane = tid & 63, wave = tid >> 6;
  const int fr = lane & 15, fq = lane >> 4;
  const int q0 = blockIdx.x * 128;
  const int b = blockIdx.y >> 4, h = blockIdx.y & 15;
  const unsigned short* base = qkv + (size_t)b * SEQ * 3072 + h * 64;
  const int qbase = q0 + wave * 32;

  bf16x8 qf[2][2];
  #pragma unroll
  for (int rt = 0; rt < 2; rt++)
    #pragma unroll
    for (int dc = 0; dc < 2; dc++)
      qf[rt][dc] = *reinterpret_cast<const bf16x8*>(
          base + (size_t)(qbase + rt*16 + fr) * 3072 + dc*32 + fq*8);

  f32x4 o[2][4];
  float mrun[2][4], lrun[2][4];
  #pragma unroll
  for (int rt = 0; rt < 2; rt++) {
    #pragma unroll
    for (int dt = 0; dt < 4; dt++) o[rt][dt] = (f32x4){0.f, 0.f, 0.f, 0.f};
    #pragma unroll
    for (int r = 0; r < 4; r++) { mrun[rt][r] = -1e30f; lrun[rt][r] = 0.f; }
  }

  const int nkv = blockIdx.x * 2 + 2;
  for (int t = 0; t < nkv; t++) {
    const int kt0 = t * 64;
    __syncthreads();
    {
      const int tok = tid >> 2, dq = (tid & 3) << 4;
      const unsigned short* kvp = base + (size_t)(kt0 + tok) * 3072;
      int4 ka = *reinterpret_cast<const int4*>(kvp + 1024 + dq);
      int4 kb = *reinterpret_cast<const int4*>(kvp + 1024 + dq + 8);
      int4 va = *reinterpret_cast<const int4*>(kvp + 2048 + dq);
      int4 vb = *reinterpret_cast<const int4*>(kvp + 2048 + dq + 8);
      *reinterpret_cast<int4*>(&Ks[tok][dq])     = ka;
      *reinterpret_cast<int4*>(&Ks[tok][dq + 8]) = kb;
      unsigned int vw[8] = {(unsigned)va.x,(unsigned)va.y,(unsigned)va.z,(unsigned)va.w,
                            (unsigned)vb.x,(unsigned)vb.y,(unsigned)vb.z,(unsigned)vb.w};
      #pragma unroll
      for (int j = 0; j < 8; j++) {
        Vt[dq + j*2 + 0][tok] = (unsigned short)(vw[j] & 0xffffu);
        Vt[dq + j*2 + 1][tok] = (unsigned short)(vw[j] >> 16);
      }
    }
    __syncthreads();

    bf16x8 kf[4][2], vf[4][2];
    #pragma unroll
    for (int i = 0; i < 4; i++)
      #pragma unroll
      for (int c = 0; c < 2; c++) {
        kf[i][c] = *reinterpret_cast<const bf16x8*>(&Ks[i*16 + fr][c*32 + fq*8]);
        vf[i][c] = *reinterpret_cast<const bf16x8*>(&Vt[i*16 + fr][c*32 + fq*8]);
      }

    #pragma unroll
    for (int rt = 0; rt < 2; rt++) {
      if (kt0 > qbase + rt*16 + 15) continue;   // fully masked for this row-tile
      f32x4 st[4];
      #pragma unroll
      for (int kt = 0; kt < 4; kt++) st[kt] = (f32x4){0.f, 0.f, 0.f, 0.f};
      #pragma unroll
      for (int kt = 0; kt < 4; kt++)
        #pragma unroll
        for (int dc = 0; dc < 2; dc++)
          st[kt] = __builtin_amdgcn_mfma_f32_16x16x32_bf16(qf[rt][dc], kf[kt][dc], st[kt], 0, 0, 0);

      float sv[4][4];
      #pragma unroll
      for (int kt = 0; kt < 4; kt++)
        #pragma unroll
        for (int r = 0; r < 4; r++) sv[kt][r] = st[kt][r] * 0.125f;

      const int qrb = qbase + rt*16 + fq*4;
      if (kt0 + 63 > qbase + rt*16) {           // causal mask needed
        #pragma unroll
        for (int kt = 0; kt < 4; kt++) {
          int kg = kt0 + kt*16 + fr;
          #pragma unroll
          for (int r = 0; r < 4; r++)
            if (kg > qrb + r) sv[kt][r] = -1e9f;
        }
      }

      #pragma unroll
      for (int r = 0; r < 4; r++) {
        float m = fmaxf(fmaxf(sv[0][r], sv[1][r]), fmaxf(sv[2][r], sv[3][r]));
        m = fmaxf(m, __shfl_xor(m, 1, 64));
        m = fmaxf(m, __shfl_xor(m, 2, 64));
        m = fmaxf(m, __shfl_xor(m, 4, 64));
        m = fmaxf(m, __shfl_xor(m, 8, 64));
        float mn = fmaxf(mrun[rt][r], m);
        float corr = __expf(mrun[rt][r] - mn);
        mrun[rt][r] = mn;
        float rs = 0.f;
        #pragma unroll
        for (int kt = 0; kt < 4; kt++) { sv[kt][r] = __expf(sv[kt][r] - mn); rs += sv[kt][r]; }
        rs += __shfl_xor(rs, 1, 64);
        rs += __shfl_xor(rs, 2, 64);
        rs += __shfl_xor(rs, 4, 64);
        rs += __shfl_xor(rs, 8, 64);
        lrun[rt][r] = lrun[rt][r] * corr + rs;
        #pragma unroll
        for (int dt = 0; dt < 4; dt++) o[rt][dt][r] *= corr;
      }

      #pragma unroll
      for (int kt = 0; kt < 4; kt++)
        #pragma unroll
        for (int r = 0; r < 4; r++)
          Ps[wave][fq*4 + r][kt*16 + fr] = f2bf(sv[kt][r]);

      bf16x8 pa[2];
      #pragma unroll
      for (int c = 0; c < 2; c++)
        pa[c] = *reinterpret_cast<const bf16x8*>(&Ps[wave][fr][c*32 + fq*8]);
      #pragma unroll
      for (int dt = 0; dt < 4; dt++)
        #pragma unroll
        for (int c = 0; c < 2; c++)
          o[rt][dt] = __builtin_amdgcn_mfma_f32_16x16x32_bf16(pa[c], vf[dt][c], o[rt][dt], 0, 0, 0);
    }
  }

  #pragma unroll
  for (int rt = 0; rt < 2; rt++) {
    #pragma unroll
    for (int r = 0; r < 4; r++) {
      float inv = 1.0f / lrun[rt][r];
      int q = qbase + rt*16 + fq*4 + r;
      unsigned short* dst = y + (size_t)(b * SEQ + q) * CH + h * 64;
      #pragma unroll
      for (int dt = 0; dt < 4; dt++)
        dst[dt*16 + fr] = f2bf(o[rt][dt][r] * inv);
    }
  }
}

// ---------------- launch ----------------
extern "C" void kernel_launch(void* const* d_in, const int* in_sizes, int n_in,
                              void* d_out, int out_size, void* d_ws, size_t ws_size,
                              hipStream_t stream)
{
  const float* emb    = (const float*)d_in[0];
  const float* ln1_g  = (const float*)d_in[2];
  const float* ln1_b  = (const float*)d_in[3];
  const float* attn_w = (const float*)d_in[4];
  const float* attn_b = (const float*)d_in[5];
  const float* proj_w = (const float*)d_in[6];
  const float* proj_b = (const float*)d_in[7];
  const float* ln2_g  = (const float*)d_in[8];
  const float* ln2_b  = (const float*)d_in[9];
  const float* fc_w   = (const float*)d_in[10];
  const float* fc_b   = (const float*)d_in[11];
  const float* p2_w   = (const float*)d_in[12];
  const float* p2_b   = (const float*)d_in[13];
  const float* lnf_g  = (const float*)d_in[14];
  const float* lnf_b  = (const float*)d_in[15];

  char* ws = (char*)d_ws;
  float* x            = (float*)ws;                         // 16777216 B
  unsigned short* qkv = (unsigned short*)(ws + 16777216);   // 25165824 B
  unsigned short* hb  = (unsigned short*)(ws + 41943040);   //  8388608 B
  unsigned short* mb  = (unsigned short*)(ws + 50331648);   // 33554432 B
  // transposed-weight scratch aliases dead buffer windows:
  unsigned short* wt_mb  = mb;    // used while mb is dead (QKV, proj GEMMs)
  unsigned short* wt_qkv = qkv;   // used while qkv is dead (fc, proj2 GEMMs)

  hipMemcpyAsync(x, emb, (size_t)MROWS * CH * sizeof(float),
                 hipMemcpyDeviceToDevice, stream);

  for (int l = 0; l < LAYERS; l++) {
    // ---- attention ----
    wt_kernel<<<dim3(3072/32, 1024/32), 256, 0, stream>>>(
        attn_w + (size_t)l*CH*3072, wt_mb, CH, 3072);
    ln_kernel<true><<<MROWS, 256, 0, stream>>>(
        x, ln1_g + (size_t)l*CH, ln1_b + (size_t)l*CH, hb, nullptr);
    gemm_bt_kernel<0,0,0,1><<<dim3(3072/128, MROWS/128), 256, 0, stream>>>(
        hb, wt_mb, attn_b + (size_t)l*3072, nullptr, nullptr, qkv, MROWS, 3072, CH);
    attn_mfma_kernel<<<dim3(SEQ/128, BATCH*NH), 256, 0, stream>>>(qkv, hb);
    wt_kernel<<<dim3(1024/32, 1024/32), 256, 0, stream>>>(
        proj_w + (size_t)l*CH*CH, wt_mb, CH, 1024);
    gemm_bt_kernel<0,1,1,0><<<dim3(CH/128, MROWS/128), 256, 0, stream>>>(
        hb, wt_mb, proj_b + (size_t)l*CH, x, x, nullptr, MROWS, CH, CH);
    // ---- MLP ----
    ln_kernel<true><<<MROWS, 256, 0, stream>>>(
        x, ln2_g + (size_t)l*CH, ln2_b + (size_t)l*CH, hb, nullptr);
    wt_kernel<<<dim3(4096/32, 1024/32), 256, 0, stream>>>(
        fc_w + (size_t)l*CH*4096, wt_qkv, CH, 4096);
    gemm_bt_kernel<1,0,0,1><<<dim3(4096/128, MROWS/128), 256, 0, stream>>>(
        hb, wt_qkv, fc_b + (size_t)l*4096, nullptr, nullptr, mb, MROWS, 4096, CH);
    wt_kernel<<<dim3(1024/32, 4096/32), 256, 0, stream>>>(
        p2_w + (size_t)l*4096*CH, wt_qkv, 4096, 1024);
    gemm_bt_kernel<0,1,1,0><<<dim3(CH/128, MROWS/128), 256, 0, stream>>>(
        mb, wt_qkv, p2_b + (size_t)l*CH, x, x, nullptr, MROWS, CH, 4096);
  }
  ln_kernel<false><<<MROWS, 256, 0, stream>>>(
      x, lnf_g, lnf_b, nullptr, (float*)d_out);
}